// Round 1
// baseline (250.465 us; speedup 1.0000x reference)
//
#include <hip/hip_runtime.h>
#include <hip/hip_bf16.h>

typedef __attribute__((ext_vector_type(8))) short bf16x8;
typedef __attribute__((ext_vector_type(4))) float f32x4;
typedef __attribute__((ext_vector_type(4))) unsigned short ushort4v;

__device__ __forceinline__ unsigned short f2bf(float f) {
  unsigned u = __float_as_uint(f);
  return (unsigned short)((u + 0x7FFFu + ((u >> 16) & 1u)) >> 16);
}
__device__ __forceinline__ float silu_f(float v) { return v / (1.f + __expf(-v)); }

// ---- K0: fp32 -> bf16 weight conversion ----
__global__ void cvt_bf16_k(const float* __restrict__ src, unsigned short* __restrict__ dst, int n) {
  int i = blockIdx.x * 256 + threadIdx.x;
  if (i < n) dst[i] = f2bf(src[i]);
}

// ---- K1: 4x4 average pool: x[16,256,56,56] -> xp[16,256,14,14] ----
__global__ void pool_k(const float* __restrict__ x, float* __restrict__ xp) {
  int idx = blockIdx.x * 256 + threadIdx.x;
  if (idx >= 16 * 256 * 196) return;
  int pj = idx % 14, tmp = idx / 14, pi = tmp % 14, bc = tmp / 14;
  const float* src = x + (size_t)bc * 3136 + pi * 4 * 56 + pj * 4;
  float s = 0.f;
#pragma unroll
  for (int u = 0; u < 4; ++u) {
    float4 v = *reinterpret_cast<const float4*>(src + u * 56);
    s += v.x + v.y + v.z + v.w;
  }
  xp[idx] = s * 0.0625f;
}

// ---- K2: router 3x3 conv (pad 1) + SiLU + spatial sum -> hsum[16,32] ----
__global__ __launch_bounds__(256) void router_conv_k(const float* __restrict__ xp,
                                                     const float* __restrict__ rw1,
                                                     float* __restrict__ hsum) {
  const int b = blockIdx.x >> 5, r = blockIdx.x & 31;
  __shared__ float wl[2304];
  __shared__ float xl[32][256];  // 32 channels, padded 16x16 planes
  __shared__ float red[4];
  const int t = threadIdx.x;
  for (int i = t; i < 2304; i += 256) wl[i] = rw1[r * 2304 + i];
  for (int i = t; i < 32 * 256; i += 256) (&xl[0][0])[i] = 0.f;  // borders stay zero
  const int pi = t / 14, pj = t % 14;
  float acc = 0.f;
  for (int cc = 0; cc < 8; ++cc) {
    __syncthreads();
    for (int i = t; i < 32 * 196; i += 256) {
      int c = i / 196, px = i % 196;
      xl[c][(px / 14 + 1) * 16 + (px % 14 + 1)] =
          xp[((size_t)b * 256 + cc * 32 + c) * 196 + px];
    }
    __syncthreads();
    if (t < 196) {
      for (int c = 0; c < 32; ++c) {
        const float* wp = &wl[(cc * 32 + c) * 9];
        const float* xc = &xl[c][pi * 16 + pj];
#pragma unroll
        for (int u = 0; u < 3; ++u)
#pragma unroll
          for (int v = 0; v < 3; ++v) acc += xc[u * 16 + v] * wp[u * 3 + v];
      }
    }
  }
  float s = (t < 196) ? silu_f(acc) : 0.f;
#pragma unroll
  for (int off = 32; off > 0; off >>= 1) s += __shfl_down(s, off);
  if ((t & 63) == 0) red[t >> 6] = s;
  __syncthreads();
  if (t == 0) hsum[b * 32 + r] = red[0] + red[1] + red[2] + red[3];
}

// ---- K3: logits -> softmax -> top-2 -> normalized weights (fp32 exact path) ----
__global__ void topk_k(const float* __restrict__ hsum, const float* __restrict__ rw2,
                       float* __restrict__ selv, int* __restrict__ sele) {
  const int t = threadIdx.x;  // 64 threads: b = t>>2, e = t&3
  const int b = t >> 2, e = t & 3;
  float l = 0.f;
#pragma unroll
  for (int r = 0; r < 32; ++r) l += rw2[e * 32 + r] * hsum[b * 32 + r];
  l *= (1.f / 196.f);
  float m = fmaxf(l, __shfl_xor(l, 1));
  m = fmaxf(m, __shfl_xor(m, 2));
  float p = __expf(l - m);
  float sm = p + __shfl_xor(p, 1);
  sm += __shfl_xor(sm, 2);
  float prob = p / sm;
  float p0 = __shfl(prob, (b << 2) | 0);
  float p1 = __shfl(prob, (b << 2) | 1);
  float p2 = __shfl(prob, (b << 2) | 2);
  float p3 = __shfl(prob, (b << 2) | 3);
  if (e == 0) {
    float pr[4] = {p0, p1, p2, p3};
    int i1 = 0;
    for (int i = 1; i < 4; ++i)
      if (pr[i] > pr[i1]) i1 = i;  // strict > : first index wins ties (jax stable)
    int i2 = (i1 == 0) ? 1 : 0;
    for (int i = 0; i < 4; ++i) {
      if (i == i1 || i == i2) continue;
      if (pr[i] > pr[i2]) i2 = i;
    }
    float denom = pr[i1] + pr[i2] + 1e-6f;
    selv[b * 2 + 0] = pr[i1] / denom;
    selv[b * 2 + 1] = pr[i2] / denom;
    sele[b * 2 + 0] = i1;
    sele[b * 2 + 1] = i2;
  }
}

// ---- K4: fused shared-expert + top-2 expert MoE, bf16 MFMA ----
// Block = (batch b, 64-pixel tile). 4 waves, 256 threads.
// xs: x tile as B-operand [col][k], XOR-swizzled; hs: hidden chunk double-buffer.
__global__ __launch_bounds__(256, 2) void moe_main_k(
    const float* __restrict__ x, const unsigned short* __restrict__ wsh,
    const unsigned short* __restrict__ w1, const unsigned short* __restrict__ w2,
    const float* __restrict__ selv, const int* __restrict__ sele,
    float* __restrict__ out) {
  constexpr int C = 256, HW = 3136, HID = 512;
  __shared__ __align__(16) unsigned short xs[64 * 256];   // 32 KB
  __shared__ __align__(16) unsigned short hs[2][64 * 64]; // 16 KB

  const int bx = blockIdx.x;
  const int b = bx / 49, tile = bx - b * 49;
  const int px0 = tile * 64;
  const int t = threadIdx.x;
  const int w = t >> 6;
  const int l = t & 63;
  const int l15 = l & 15, lq = l >> 4;

  // ---- stage x tile (fp32 -> bf16, transpose to [col][k], swizzled) ----
  {
    const int col = t & 63, kg = t >> 6;
    const float* xb = x + (size_t)b * C * HW + px0 + col;
#pragma unroll
    for (int ci = 0; ci < 8; ++ci) {
      const int k0 = kg * 64 + ci * 8;
      alignas(16) unsigned short tmp[8];
#pragma unroll
      for (int i = 0; i < 8; ++i) tmp[i] = f2bf(xb[(size_t)(k0 + i) * HW]);
      const int idx = (col * 256 + k0) ^ ((col & 7) << 3);
      *reinterpret_cast<bf16x8*>(&xs[idx]) = *reinterpret_cast<const bf16x8*>(tmp);
    }
  }

  f32x4 oacc[4][4];
#pragma unroll
  for (int i = 0; i < 4; ++i)
#pragma unroll
    for (int j = 0; j < 4; ++j) {
      f32x4 z = {0.f, 0.f, 0.f, 0.f};
      oacc[i][j] = z;
    }

  __syncthreads();

  // ---- shared expert: out rows [w*64, w*64+64), K = 256 ----
  {
    const unsigned short* A = wsh + (size_t)(w * 64 + l15) * C + lq * 8;
#pragma unroll 2
    for (int ks = 0; ks < 8; ++ks) {
      bf16x8 bfr[4];
#pragma unroll
      for (int cf = 0; cf < 4; ++cf) {
        const int colx = cf * 16 + l15;
        const int idx = (colx * 256 + ks * 32 + lq * 8) ^ ((colx & 7) << 3);
        bfr[cf] = *reinterpret_cast<const bf16x8*>(&xs[idx]);
      }
#pragma unroll
      for (int rf = 0; rf < 4; ++rf) {
        const bf16x8 afr = *reinterpret_cast<const bf16x8*>(A + rf * 16 * C + ks * 32);
#pragma unroll
        for (int cf = 0; cf < 4; ++cf)
          oacc[rf][cf] = __builtin_amdgcn_mfma_f32_16x16x32_bf16(afr, bfr[cf], oacc[rf][cf], 0, 0, 0);
      }
    }
  }
#pragma unroll
  for (int i = 0; i < 4; ++i)
#pragma unroll
    for (int j = 0; j < 4; ++j)
#pragma unroll
      for (int r = 0; r < 4; ++r) oacc[i][j][r] = silu_f(oacc[i][j][r]);

  // ---- top-2 experts, hidden in chunks of 64, routing weight folded into hid ----
#pragma unroll 1
  for (int ei = 0; ei < 2; ++ei) {
    const int e = sele[b * 2 + ei];
    const float v = selv[b * 2 + ei];
    const unsigned short* W1e = w1 + (size_t)e * HID * C;
    const unsigned short* W2e = w2 + (size_t)e * 256 * HID;
#pragma unroll 1
    for (int ch = 0; ch < 8; ++ch) {
      const int p = ch & 1;
      f32x4 hacc[4];
#pragma unroll
      for (int cf = 0; cf < 4; ++cf) {
        f32x4 z = {0.f, 0.f, 0.f, 0.f};
        hacc[cf] = z;
      }
      // stage1: hid rows ch*64 + w*16 + (0..15), K = 256
      const unsigned short* A1 = W1e + (size_t)(ch * 64 + w * 16 + l15) * C + lq * 8;
#pragma unroll 2
      for (int ks = 0; ks < 8; ++ks) {
        const bf16x8 afr = *reinterpret_cast<const bf16x8*>(A1 + ks * 32);
#pragma unroll
        for (int cf = 0; cf < 4; ++cf) {
          const int colx = cf * 16 + l15;
          const int idx = (colx * 256 + ks * 32 + lq * 8) ^ ((colx & 7) << 3);
          const bf16x8 bfr = *reinterpret_cast<const bf16x8*>(&xs[idx]);
          hacc[cf] = __builtin_amdgcn_mfma_f32_16x16x32_bf16(afr, bfr, hacc[cf], 0, 0, 0);
        }
      }
      // v * silu(hid) -> bf16 -> hs[p] (transposed [col][k2], swizzled)
#pragma unroll
      for (int cf = 0; cf < 4; ++cf) {
        const int colx = cf * 16 + l15;
        const int k2 = w * 16 + lq * 4;
        alignas(8) unsigned short pk[4];
#pragma unroll
        for (int r = 0; r < 4; ++r) pk[r] = f2bf(v * silu_f(hacc[cf][r]));
        const int idx = (colx * 64 + k2) ^ ((colx & 7) << 3);
        *reinterpret_cast<ushort4v*>(&hs[p][idx]) = *reinterpret_cast<const ushort4v*>(pk);
      }
      __syncthreads();
      // stage2: out rows [w*64, +64), K = 64 over this chunk, accumulate into oacc
      const unsigned short* A2 = W2e + (size_t)(w * 64 + l15) * HID + ch * 64 + lq * 8;
#pragma unroll
      for (int ks = 0; ks < 2; ++ks) {
        bf16x8 bfr[4];
#pragma unroll
        for (int cf = 0; cf < 4; ++cf) {
          const int colx = cf * 16 + l15;
          const int idx = (colx * 64 + ks * 32 + lq * 8) ^ ((colx & 7) << 3);
          bfr[cf] = *reinterpret_cast<const bf16x8*>(&hs[p][idx]);
        }
#pragma unroll
        for (int rf = 0; rf < 4; ++rf) {
          const bf16x8 afr = *reinterpret_cast<const bf16x8*>(A2 + rf * 16 * HID + ks * 32);
#pragma unroll
          for (int cf = 0; cf < 4; ++cf)
            oacc[rf][cf] = __builtin_amdgcn_mfma_f32_16x16x32_bf16(afr, bfr[cf], oacc[rf][cf], 0, 0, 0);
        }
      }
      // no barrier here: double-buffered hs; next chunk's writes go to hs[p^1],
      // and the barrier inside chunk ch+1 orders reads(ch) before writes(ch+2).
    }
  }

  // ---- write out[b, o, px] ----
#pragma unroll
  for (int rf = 0; rf < 4; ++rf) {
    const int o = w * 64 + rf * 16 + lq * 4;
#pragma unroll
    for (int cf = 0; cf < 4; ++cf) {
      float* op = out + ((size_t)b * 256 + o) * HW + px0 + cf * 16 + l15;
#pragma unroll
      for (int r = 0; r < 4; ++r) op[(size_t)r * HW] = oacc[rf][cf][r];
    }
  }
}

extern "C" void kernel_launch(void* const* d_in, const int* in_sizes, int n_in,
                              void* d_out, int out_size, void* d_ws, size_t ws_size,
                              hipStream_t stream) {
  const float* x = (const float*)d_in[0];
  const float* rw1 = (const float*)d_in[1];
  const float* rw2 = (const float*)d_in[2];
  const float* ew1 = (const float*)d_in[3];
  const float* ew2 = (const float*)d_in[4];
  const float* shw = (const float*)d_in[5];
  float* out = (float*)d_out;
  char* ws = (char*)d_ws;

  // workspace layout (total ~5.2 MB)
  float* xp = (float*)(ws);                      // 802816 f = 3,211,264 B
  float* hsum = (float*)(ws + 3211264);          // 512 f
  float* selv = (float*)(ws + 3213312);          // 32 f
  int* sele = (int*)(ws + 3213440);              // 32 i
  unsigned short* wshb = (unsigned short*)(ws + 3213568);  // 65536
  unsigned short* w1b = wshb + 65536;                      // 524288
  unsigned short* w2b = w1b + 524288;                      // 524288

  cvt_bf16_k<<<256, 256, 0, stream>>>(shw, wshb, 65536);
  cvt_bf16_k<<<2048, 256, 0, stream>>>(ew1, w1b, 524288);
  cvt_bf16_k<<<2048, 256, 0, stream>>>(ew2, w2b, 524288);
  pool_k<<<3136, 256, 0, stream>>>(x, xp);
  router_conv_k<<<512, 256, 0, stream>>>(xp, rw1, hsum);
  topk_k<<<1, 64, 0, stream>>>(hsum, rw2, selv, sele);
  moe_main_k<<<784, 256, 0, stream>>>(x, wshb, w1b, w2b, selv, sele, out);
}

// Round 2
// 184.431 us; speedup vs baseline: 1.3580x; 1.3580x over previous
//
#include <hip/hip_runtime.h>
#include <hip/hip_bf16.h>

typedef __attribute__((ext_vector_type(8))) short bf16x8;
typedef __attribute__((ext_vector_type(16))) float f32x16;
typedef __attribute__((ext_vector_type(4))) unsigned short ushort4v;

__device__ __forceinline__ unsigned short f2bf(float f) {
  unsigned u = __float_as_uint(f);
  return (unsigned short)((u + 0x7FFFu + ((u >> 16) & 1u)) >> 16);
}
__device__ __forceinline__ float silu_f(float v) { return v / (1.f + __expf(-v)); }

// ---- K0: convert + pack all weights into 32x32x16 A-fragment order ----
// A-frag for (row-block rb of 32 rows, ks of 16 k): lane l holds row rb*32+(l&31),
// k = ks*16 + (l>>5)*8 + i, i=0..7.  packed[( (rb*NKS+ks)*64 + l)*8 + i]
__global__ void pack_k(const float* __restrict__ shw, const float* __restrict__ ew1,
                       const float* __restrict__ ew2, unsigned short* __restrict__ wshp,
                       unsigned short* __restrict__ w1p, unsigned short* __restrict__ w2p) {
  int idx = blockIdx.x * 256 + threadIdx.x;
  if (idx < 65536) {  // shared_w [256,256]
    int j = idx;
    int i = j & 7, l = (j >> 3) & 63, ks = (j >> 9) & 15, rb = j >> 13;
    int row = rb * 32 + (l & 31), k = ks * 16 + (l >> 5) * 8 + i;
    wshp[j] = f2bf(shw[row * 256 + k]);
  } else if (idx < 589824) {  // expert_w1 [4,512,256]
    int j = idx - 65536;
    int i = j & 7, l = (j >> 3) & 63, ks = (j >> 9) & 15, rb = (j >> 13) & 15, e = j >> 17;
    int row = rb * 32 + (l & 31), k = ks * 16 + (l >> 5) * 8 + i;
    w1p[j] = f2bf(ew1[((size_t)e * 512 + row) * 256 + k]);
  } else if (idx < 1114112) {  // expert_w2 [4,256,512]
    int j = idx - 589824;
    int i = j & 7, l = (j >> 3) & 63, ks = (j >> 9) & 31, rb = (j >> 14) & 7, e = j >> 17;
    int row = rb * 32 + (l & 31), k = ks * 16 + (l >> 5) * 8 + i;
    w2p[j] = f2bf(ew2[((size_t)e * 256 + row) * 512 + k]);
  }
}

// ---- K1: 4x4 average pool: x[16,256,56,56] -> xp[16,256,14,14] ----
__global__ void pool_k(const float* __restrict__ x, float* __restrict__ xp) {
  int idx = blockIdx.x * 256 + threadIdx.x;
  if (idx >= 16 * 256 * 196) return;
  int pj = idx % 14, tmp = idx / 14, pi = tmp % 14, bc = tmp / 14;
  const float* src = x + (size_t)bc * 3136 + pi * 4 * 56 + pj * 4;
  float s = 0.f;
#pragma unroll
  for (int u = 0; u < 4; ++u) {
    float4 v = *reinterpret_cast<const float4*>(src + u * 56);
    s += v.x + v.y + v.z + v.w;
  }
  xp[idx] = s * 0.0625f;
}

// ---- K2: router 3x3 conv (pad 1) + SiLU + spatial sum -> hsum[16,32] ----
__global__ __launch_bounds__(256) void router_conv_k(const float* __restrict__ xp,
                                                     const float* __restrict__ rw1,
                                                     float* __restrict__ hsum) {
  const int b = blockIdx.x >> 5, r = blockIdx.x & 31;
  __shared__ float wl[2304];
  __shared__ float xl[32][256];
  __shared__ float red[4];
  const int t = threadIdx.x;
  for (int i = t; i < 2304; i += 256) wl[i] = rw1[r * 2304 + i];
  for (int i = t; i < 32 * 256; i += 256) (&xl[0][0])[i] = 0.f;
  const int pi = t / 14, pj = t % 14;
  float acc = 0.f;
  for (int cc = 0; cc < 8; ++cc) {
    __syncthreads();
    for (int i = t; i < 32 * 196; i += 256) {
      int c = i / 196, px = i % 196;
      xl[c][(px / 14 + 1) * 16 + (px % 14 + 1)] =
          xp[((size_t)b * 256 + cc * 32 + c) * 196 + px];
    }
    __syncthreads();
    if (t < 196) {
      for (int c = 0; c < 32; ++c) {
        const float* wp = &wl[(cc * 32 + c) * 9];
        const float* xc = &xl[c][pi * 16 + pj];
#pragma unroll
        for (int u = 0; u < 3; ++u)
#pragma unroll
          for (int v = 0; v < 3; ++v) acc += xc[u * 16 + v] * wp[u * 3 + v];
      }
    }
  }
  float s = (t < 196) ? silu_f(acc) : 0.f;
#pragma unroll
  for (int off = 32; off > 0; off >>= 1) s += __shfl_down(s, off);
  if ((t & 63) == 0) red[t >> 6] = s;
  __syncthreads();
  if (t == 0) hsum[b * 32 + r] = red[0] + red[1] + red[2] + red[3];
}

// ---- K3: logits -> softmax -> top-2 -> normalized weights ----
__global__ void topk_k(const float* __restrict__ hsum, const float* __restrict__ rw2,
                       float* __restrict__ selv, int* __restrict__ sele) {
  const int t = threadIdx.x;
  const int b = t >> 2, e = t & 3;
  float l = 0.f;
#pragma unroll
  for (int r = 0; r < 32; ++r) l += rw2[e * 32 + r] * hsum[b * 32 + r];
  l *= (1.f / 196.f);
  float m = fmaxf(l, __shfl_xor(l, 1));
  m = fmaxf(m, __shfl_xor(m, 2));
  float p = __expf(l - m);
  float sm = p + __shfl_xor(p, 1);
  sm += __shfl_xor(sm, 2);
  float prob = p / sm;
  float p0 = __shfl(prob, (b << 2) | 0);
  float p1 = __shfl(prob, (b << 2) | 1);
  float p2 = __shfl(prob, (b << 2) | 2);
  float p3 = __shfl(prob, (b << 2) | 3);
  if (e == 0) {
    float pr[4] = {p0, p1, p2, p3};
    int i1 = 0;
    for (int i = 1; i < 4; ++i)
      if (pr[i] > pr[i1]) i1 = i;
    int i2 = (i1 == 0) ? 1 : 0;
    for (int i = 0; i < 4; ++i) {
      if (i == i1 || i == i2) continue;
      if (pr[i] > pr[i2]) i2 = i;
    }
    float denom = pr[i1] + pr[i2] + 1e-6f;
    selv[b * 2 + 0] = pr[i1] / denom;
    selv[b * 2 + 1] = pr[i2] / denom;
    sele[b * 2 + 0] = i1;
    sele[b * 2 + 1] = i2;
  }
}

// ---- K4: fused MoE main, 32x32x16 MFMA, 8 waves, 64px tiles ----
// wave w owns 32 output/hidden rows: rows w*32..w*32+32 (of 256 per phase)
// xs/hs layout: ushort idx = (px*256 + k) ^ ((px&7)<<3)
__global__ __launch_bounds__(512, 4) void moe_main_k(
    const float* __restrict__ x, const unsigned short* __restrict__ wshp,
    const unsigned short* __restrict__ w1p, const unsigned short* __restrict__ w2p,
    const float* __restrict__ selv, const int* __restrict__ sele,
    float* __restrict__ out) {
  constexpr int C = 256, HW = 3136;
  __shared__ __align__(16) unsigned short xs[64 * 256];  // 32 KB
  __shared__ __align__(16) unsigned short hs[64 * 256];  // 32 KB

  const int bx = blockIdx.x;
  const int b = bx / 49, tile = bx - b * 49;
  const int px0 = tile * 64;
  const int t = threadIdx.x;
  const int w = t >> 6, l = t & 63;
  const int l31 = l & 31, lh = l >> 5;

  // ---- stage x tile (fp32 -> bf16, [px][k] swizzled) ----
  {
    const int px = l;
    const float* xb = x + (size_t)b * C * HW + px0 + px;
#pragma unroll
    for (int cg = 0; cg < 4; ++cg) {
      const int ch0 = w * 32 + cg * 8;
      alignas(16) unsigned short tmp[8];
#pragma unroll
      for (int i2 = 0; i2 < 8; ++i2) tmp[i2] = f2bf(xb[(size_t)(ch0 + i2) * HW]);
      const int idx = (px * 256 + ch0) ^ ((px & 7) << 3);
      *reinterpret_cast<bf16x8*>(&xs[idx]) = *reinterpret_cast<const bf16x8*>(tmp);
    }
  }

  f32x16 oacc[2];
#pragma unroll
  for (int cf = 0; cf < 2; ++cf)
#pragma unroll
    for (int r = 0; r < 16; ++r) oacc[cf][r] = 0.f;

  __syncthreads();

  // ---- shared expert: out rows w*32..+32, K=256 ----
  {
    const unsigned short* A = wshp + (size_t)(w * 16) * 512 + l * 8;
#pragma unroll
    for (int ks = 0; ks < 16; ++ks) {
      const bf16x8 afr = *reinterpret_cast<const bf16x8*>(A + ks * 512);
#pragma unroll
      for (int cf = 0; cf < 2; ++cf) {
        const int px = cf * 32 + l31;
        const int idx = (px * 256 + ks * 16 + lh * 8) ^ ((px & 7) << 3);
        const bf16x8 bfr = *reinterpret_cast<const bf16x8*>(&xs[idx]);
        oacc[cf] = __builtin_amdgcn_mfma_f32_32x32x16_bf16(afr, bfr, oacc[cf], 0, 0, 0);
      }
    }
  }
#pragma unroll
  for (int cf = 0; cf < 2; ++cf)
#pragma unroll
    for (int r = 0; r < 16; ++r) oacc[cf][r] = silu_f(oacc[cf][r]);

  // ---- top-2 experts: hidden in 2 phases of 256 rows ----
#pragma unroll 1
  for (int ei = 0; ei < 2; ++ei) {
    const int e = sele[b * 2 + ei];
    const float v = selv[b * 2 + ei];
#pragma unroll 1
    for (int ph = 0; ph < 2; ++ph) {
      // stage1: hid rows ph*256 + w*32 ..+32, K=C=256 (reads xs only)
      f32x16 hacc[2];
#pragma unroll
      for (int cf = 0; cf < 2; ++cf)
#pragma unroll
        for (int r = 0; r < 16; ++r) hacc[cf][r] = 0.f;
      const unsigned short* A1 = w1p + (size_t)((e * 16 + ph * 8 + w) * 16) * 512 + l * 8;
#pragma unroll
      for (int ks = 0; ks < 16; ++ks) {
        const bf16x8 afr = *reinterpret_cast<const bf16x8*>(A1 + ks * 512);
#pragma unroll
        for (int cf = 0; cf < 2; ++cf) {
          const int px = cf * 32 + l31;
          const int idx = (px * 256 + ks * 16 + lh * 8) ^ ((px & 7) << 3);
          const bf16x8 bfr = *reinterpret_cast<const bf16x8*>(&xs[idx]);
          hacc[cf] = __builtin_amdgcn_mfma_f32_32x32x16_bf16(afr, bfr, hacc[cf], 0, 0, 0);
        }
      }
      __syncthreads();  // previous stage2 readers of hs are done
      // v * silu(hid) -> bf16 -> hs  (C-frag row = (reg&3)+8*(reg>>2)+4*lh)
#pragma unroll
      for (int cf = 0; cf < 2; ++cf) {
        const int px = cf * 32 + l31;
#pragma unroll
        for (int g = 0; g < 4; ++g) {
          alignas(8) unsigned short pk[4];
#pragma unroll
          for (int j = 0; j < 4; ++j) pk[j] = f2bf(v * silu_f(hacc[cf][g * 4 + j]));
          const int kk = w * 32 + g * 8 + lh * 4;
          const int idx = (px * 256 + kk) ^ ((px & 7) << 3);
          *reinterpret_cast<ushort4v*>(&hs[idx]) = *reinterpret_cast<const ushort4v*>(pk);
        }
      }
      __syncthreads();
      // stage2: out rows w*32..+32, K=256 over this phase's hid rows
      const unsigned short* A2 = w2p + (size_t)((e * 8 + w) * 32 + ph * 16) * 512 + l * 8;
#pragma unroll
      for (int ks = 0; ks < 16; ++ks) {
        const bf16x8 afr = *reinterpret_cast<const bf16x8*>(A2 + ks * 512);
#pragma unroll
        for (int cf = 0; cf < 2; ++cf) {
          const int px = cf * 32 + l31;
          const int idx = (px * 256 + ks * 16 + lh * 8) ^ ((px & 7) << 3);
          const bf16x8 bfr = *reinterpret_cast<const bf16x8*>(&hs[idx]);
          oacc[cf] = __builtin_amdgcn_mfma_f32_32x32x16_bf16(afr, bfr, oacc[cf], 0, 0, 0);
        }
      }
    }
  }

  // ---- write out[b, o, px] ----
#pragma unroll
  for (int cf = 0; cf < 2; ++cf) {
    const int px = px0 + cf * 32 + l31;
#pragma unroll
    for (int g = 0; g < 4; ++g) {
#pragma unroll
      for (int j = 0; j < 4; ++j) {
        const int o = w * 32 + g * 8 + 4 * lh + j;
        out[((size_t)b * 256 + o) * HW + px] = oacc[cf][g * 4 + j];
      }
    }
  }
}

extern "C" void kernel_launch(void* const* d_in, const int* in_sizes, int n_in,
                              void* d_out, int out_size, void* d_ws, size_t ws_size,
                              hipStream_t stream) {
  const float* x = (const float*)d_in[0];
  const float* rw1 = (const float*)d_in[1];
  const float* rw2 = (const float*)d_in[2];
  const float* ew1 = (const float*)d_in[3];
  const float* ew2 = (const float*)d_in[4];
  const float* shw = (const float*)d_in[5];
  float* out = (float*)d_out;
  char* ws = (char*)d_ws;

  // workspace layout (~5.44 MB)
  float* xp = (float*)(ws);                                // 3,211,264 B
  float* hsum = (float*)(ws + 3211264);                    // 2 KB
  float* selv = (float*)(ws + 3213312);
  int* sele = (int*)(ws + 3213440);
  unsigned short* wshp = (unsigned short*)(ws + 3213568);  // 131,072 B
  unsigned short* w1p = wshp + 65536;                      // 1 MB
  unsigned short* w2p = w1p + 524288;                      // 1 MB

  pack_k<<<4352, 256, 0, stream>>>(shw, ew1, ew2, wshp, w1p, w2p);
  pool_k<<<3136, 256, 0, stream>>>(x, xp);
  router_conv_k<<<512, 256, 0, stream>>>(xp, rw1, hsum);
  topk_k<<<1, 64, 0, stream>>>(hsum, rw2, selv, sele);
  moe_main_k<<<784, 512, 0, stream>>>(x, wshp, w1p, w2p, selv, sele, out);
}

// Round 3
// 168.803 us; speedup vs baseline: 1.4838x; 1.0926x over previous
//
#include <hip/hip_runtime.h>
#include <hip/hip_bf16.h>

typedef __attribute__((ext_vector_type(8))) short bf16x8;
typedef __attribute__((ext_vector_type(16))) float f32x16;
typedef __attribute__((ext_vector_type(4))) unsigned short ushort4v;

static __device__ __forceinline__ unsigned short f2bf(float f) {
  unsigned u = __float_as_uint(f);
  return (unsigned short)((u + 0x7FFFu + ((u >> 16) & 1u)) >> 16);
}
static __device__ __forceinline__ float silu_f(float v) { return v / (1.f + __expf(-v)); }

// ---- K0: fused weight pack (A-fragment order) + 4x4 avg pool ----
// A-frag pack: lane l holds row rb*32+(l&31), k = ks*16 + (l>>5)*8 + i.
// packed[((rb*NKS+ks)*64 + l)*8 + i]
__global__ void prep_k(const float* __restrict__ shw, const float* __restrict__ ew1,
                       const float* __restrict__ ew2, const float* __restrict__ x,
                       unsigned short* __restrict__ wshp, unsigned short* __restrict__ w1p,
                       unsigned short* __restrict__ w2p, float* __restrict__ xp) {
  const int bid = blockIdx.x;
  if (bid < 4352) {
    int idx = bid * 256 + threadIdx.x;
    if (idx < 65536) {  // shared_w [256,256], NKS=16
      int j = idx;
      int i = j & 7, l = (j >> 3) & 63, ks = (j >> 9) & 15, rb = j >> 13;
      int row = rb * 32 + (l & 31), k = ks * 16 + (l >> 5) * 8 + i;
      wshp[j] = f2bf(shw[row * 256 + k]);
    } else if (idx < 589824) {  // expert_w1 [4,512,256], NKS=16
      int j = idx - 65536;
      int i = j & 7, l = (j >> 3) & 63, ks = (j >> 9) & 15, rb = (j >> 13) & 15, e = j >> 17;
      int row = rb * 32 + (l & 31), k = ks * 16 + (l >> 5) * 8 + i;
      w1p[j] = f2bf(ew1[((size_t)e * 512 + row) * 256 + k]);
    } else if (idx < 1114112) {  // expert_w2 [4,256,512], NKS=32
      int j = idx - 589824;
      int i = j & 7, l = (j >> 3) & 63, ks = (j >> 9) & 31, rb = (j >> 14) & 7, e = j >> 17;
      int row = rb * 32 + (l & 31), k = ks * 16 + (l >> 5) * 8 + i;
      w2p[j] = f2bf(ew2[((size_t)e * 256 + row) * 512 + k]);
    }
  } else {
    int idx = (bid - 4352) * 256 + threadIdx.x;
    if (idx >= 16 * 256 * 196) return;
    int pj = idx % 14, tmp = idx / 14, pi = tmp % 14, bc = tmp / 14;
    const float* src = x + (size_t)bc * 3136 + pi * 4 * 56 + pj * 4;
    float s = 0.f;
#pragma unroll
    for (int u = 0; u < 4; ++u) {
      float4 v = *reinterpret_cast<const float4*>(src + u * 56);
      s += v.x + v.y + v.z + v.w;
    }
    xp[idx] = s * 0.0625f;
  }
}

// ---- K2: router 3x3 conv (pad 1) + SiLU + spatial sum -> hsum[16,32] ----
__global__ __launch_bounds__(256) void router_conv_k(const float* __restrict__ xp,
                                                     const float* __restrict__ rw1,
                                                     float* __restrict__ hsum) {
  const int b = blockIdx.x >> 5, r = blockIdx.x & 31;
  __shared__ float wl[2304];
  __shared__ float xl[32][256];
  __shared__ float red[4];
  const int t = threadIdx.x;
  for (int i = t; i < 2304; i += 256) wl[i] = rw1[r * 2304 + i];
  for (int i = t; i < 32 * 256; i += 256) (&xl[0][0])[i] = 0.f;
  const int pi = t / 14, pj = t % 14;
  float acc = 0.f;
  for (int cc = 0; cc < 8; ++cc) {
    __syncthreads();
    for (int i = t; i < 32 * 196; i += 256) {
      int c = i / 196, px = i % 196;
      xl[c][(px / 14 + 1) * 16 + (px % 14 + 1)] =
          xp[((size_t)b * 256 + cc * 32 + c) * 196 + px];
    }
    __syncthreads();
    if (t < 196) {
      for (int c = 0; c < 32; ++c) {
        const float* wp = &wl[(cc * 32 + c) * 9];
        const float* xc = &xl[c][pi * 16 + pj];
#pragma unroll
        for (int u = 0; u < 3; ++u)
#pragma unroll
          for (int v = 0; v < 3; ++v) acc += xc[u * 16 + v] * wp[u * 3 + v];
      }
    }
  }
  float s = (t < 196) ? silu_f(acc) : 0.f;
#pragma unroll
  for (int off = 32; off > 0; off >>= 1) s += __shfl_down(s, off);
  if ((t & 63) == 0) red[t >> 6] = s;
  __syncthreads();
  if (t == 0) hsum[b * 32 + r] = red[0] + red[1] + red[2] + red[3];
}

// ---- K3: logits -> softmax -> top-2 -> normalized weights ----
__global__ void topk_k(const float* __restrict__ hsum, const float* __restrict__ rw2,
                       float* __restrict__ selv, int* __restrict__ sele) {
  const int t = threadIdx.x;
  const int b = t >> 2, e = t & 3;
  float l = 0.f;
#pragma unroll
  for (int r = 0; r < 32; ++r) l += rw2[e * 32 + r] * hsum[b * 32 + r];
  l *= (1.f / 196.f);
  float m = fmaxf(l, __shfl_xor(l, 1));
  m = fmaxf(m, __shfl_xor(m, 2));
  float p = __expf(l - m);
  float sm = p + __shfl_xor(p, 1);
  sm += __shfl_xor(sm, 2);
  float prob = p / sm;
  float p0 = __shfl(prob, (b << 2) | 0);
  float p1 = __shfl(prob, (b << 2) | 1);
  float p2 = __shfl(prob, (b << 2) | 2);
  float p3 = __shfl(prob, (b << 2) | 3);
  if (e == 0) {
    float pr[4] = {p0, p1, p2, p3};
    int i1 = 0;
    for (int i = 1; i < 4; ++i)
      if (pr[i] > pr[i1]) i1 = i;
    int i2 = (i1 == 0) ? 1 : 0;
    for (int i = 0; i < 4; ++i) {
      if (i == i1 || i == i2) continue;
      if (pr[i] > pr[i2]) i2 = i;
    }
    float denom = pr[i1] + pr[i2] + 1e-6f;
    selv[b * 2 + 0] = pr[i1] / denom;
    selv[b * 2 + 1] = pr[i2] / denom;
    sele[b * 2 + 0] = i1;
    sele[b * 2 + 1] = i2;
  }
}

// K=256 GEMM step: 2 row-blocks x 2 px-blocks, 2-deep software pipeline.
// A0/A1: per-lane weight-frag pointers (advance 512 ushorts per ks).
// B0/B1: per-lane LDS frag pointers (advance 1024 ushorts per ks).
static __device__ __forceinline__ void gemm_k256(
    const unsigned short* __restrict__ A0, const unsigned short* __restrict__ A1,
    const unsigned short* B0, const unsigned short* B1, f32x16 acc[2][2]) {
  bf16x8 aA[2], bA[2], aB[2], bB[2];
  aA[0] = *reinterpret_cast<const bf16x8*>(A0);
  aA[1] = *reinterpret_cast<const bf16x8*>(A1);
  bA[0] = *reinterpret_cast<const bf16x8*>(B0);
  bA[1] = *reinterpret_cast<const bf16x8*>(B1);
#pragma unroll
  for (int kk = 0; kk < 16; kk += 2) {
    aB[0] = *reinterpret_cast<const bf16x8*>(A0 + (kk + 1) * 512);
    aB[1] = *reinterpret_cast<const bf16x8*>(A1 + (kk + 1) * 512);
    bB[0] = *reinterpret_cast<const bf16x8*>(B0 + (kk + 1) * 1024);
    bB[1] = *reinterpret_cast<const bf16x8*>(B1 + (kk + 1) * 1024);
    acc[0][0] = __builtin_amdgcn_mfma_f32_32x32x16_bf16(aA[0], bA[0], acc[0][0], 0, 0, 0);
    acc[0][1] = __builtin_amdgcn_mfma_f32_32x32x16_bf16(aA[0], bA[1], acc[0][1], 0, 0, 0);
    acc[1][0] = __builtin_amdgcn_mfma_f32_32x32x16_bf16(aA[1], bA[0], acc[1][0], 0, 0, 0);
    acc[1][1] = __builtin_amdgcn_mfma_f32_32x32x16_bf16(aA[1], bA[1], acc[1][1], 0, 0, 0);
    if (kk + 2 < 16) {
      aA[0] = *reinterpret_cast<const bf16x8*>(A0 + (kk + 2) * 512);
      aA[1] = *reinterpret_cast<const bf16x8*>(A1 + (kk + 2) * 512);
      bA[0] = *reinterpret_cast<const bf16x8*>(B0 + (kk + 2) * 1024);
      bA[1] = *reinterpret_cast<const bf16x8*>(B1 + (kk + 2) * 1024);
    }
    acc[0][0] = __builtin_amdgcn_mfma_f32_32x32x16_bf16(aB[0], bB[0], acc[0][0], 0, 0, 0);
    acc[0][1] = __builtin_amdgcn_mfma_f32_32x32x16_bf16(aB[0], bB[1], acc[0][1], 0, 0, 0);
    acc[1][0] = __builtin_amdgcn_mfma_f32_32x32x16_bf16(aB[1], bB[0], acc[1][0], 0, 0, 0);
    acc[1][1] = __builtin_amdgcn_mfma_f32_32x32x16_bf16(aB[1], bB[1], acc[1][1], 0, 0, 0);
  }
}

// ---- K4: fused MoE main. 4 waves x 64px, rf=2 cf=2, frag-linear LDS ----
// xs/hs layout: [kgroup 0..31][px 0..63][8 ushorts] -- B-frags contiguous.
__global__ __launch_bounds__(256, 2) void moe_main_k(
    const float* __restrict__ x, const unsigned short* __restrict__ wshp,
    const unsigned short* __restrict__ w1p, const unsigned short* __restrict__ w2p,
    const float* __restrict__ selv, const int* __restrict__ sele,
    float* __restrict__ out) {
  constexpr int HW = 3136;
  __shared__ __align__(16) unsigned short xs[32 * 64 * 8];  // 32 KB
  __shared__ __align__(16) unsigned short hs[32 * 64 * 8];  // 32 KB

  const int b = blockIdx.x / 49, tile = blockIdx.x - b * 49;
  const int px0 = tile * 64;
  const int t = threadIdx.x;
  const int w = t >> 6, l = t & 63;
  const int l31 = l & 31, lh = l >> 5;

  // ---- stage x tile: thread handles px=l, channels w*64+cg*8+i ----
  {
    const float* xb = x + (size_t)b * 256 * HW + px0 + l;
#pragma unroll
    for (int cg = 0; cg < 8; ++cg) {
      const int c0 = w * 64 + cg * 8;
      alignas(16) unsigned short tmp[8];
#pragma unroll
      for (int i = 0; i < 8; ++i) tmp[i] = f2bf(xb[(size_t)(c0 + i) * HW]);
      *reinterpret_cast<bf16x8*>(&xs[((c0 >> 3) * 64 + l) * 8]) =
          *reinterpret_cast<const bf16x8*>(tmp);
    }
  }

  // per-lane B-frag base pointers (k element = (l>>5)*8 + i)
  const unsigned short* xB0 = xs + (lh * 64 + l31) * 8;
  const unsigned short* xB1 = xB0 + 32 * 8;
  const unsigned short* hB0 = hs + (lh * 64 + l31) * 8;
  const unsigned short* hB1 = hB0 + 32 * 8;

  f32x16 oacc[2][2];
#pragma unroll
  for (int i = 0; i < 2; ++i)
#pragma unroll
    for (int j = 0; j < 2; ++j)
#pragma unroll
      for (int r = 0; r < 16; ++r) oacc[i][j][r] = 0.f;

  __syncthreads();

  // ---- shared expert: out rows w*64..+64 (rb = w*2, w*2+1), K=256 ----
  {
    const unsigned short* A0 = wshp + (size_t)(w * 2) * 16 * 512 + l * 8;
    gemm_k256(A0, A0 + 8192, xB0, xB1, oacc);
  }
#pragma unroll
  for (int i = 0; i < 2; ++i)
#pragma unroll
    for (int j = 0; j < 2; ++j)
#pragma unroll
      for (int r = 0; r < 16; ++r) oacc[i][j][r] = silu_f(oacc[i][j][r]);

  // ---- top-2 experts: hidden 512 rows in 2 phases of 256 ----
#pragma unroll 1
  for (int ei = 0; ei < 2; ++ei) {
    const int e = sele[b * 2 + ei];
    const float v = selv[b * 2 + ei];
#pragma unroll 1
    for (int ph = 0; ph < 2; ++ph) {
      f32x16 hacc[2][2];
#pragma unroll
      for (int i = 0; i < 2; ++i)
#pragma unroll
        for (int j = 0; j < 2; ++j)
#pragma unroll
          for (int r = 0; r < 16; ++r) hacc[i][j][r] = 0.f;
      // stage1: hid rows ph*256 + w*64 ..+64 (rb = ph*8 + w*2 + rfi), K=256
      {
        const unsigned short* A0 =
            w1p + (size_t)(e * 16 + ph * 8 + w * 2) * 16 * 512 + l * 8;
        gemm_k256(A0, A0 + 8192, xB0, xB1, hacc);
      }
      __syncthreads();  // previous stage2 readers of hs are done
      // v*silu(hid) -> bf16 -> hs (frag-linear, conflict-free 8B writes)
#pragma unroll
      for (int rfi = 0; rfi < 2; ++rfi)
#pragma unroll
        for (int cf = 0; cf < 2; ++cf) {
#pragma unroll
          for (int g = 0; g < 4; ++g) {
            alignas(8) unsigned short pk[4];
#pragma unroll
            for (int j = 0; j < 4; ++j)
              pk[j] = f2bf(v * silu_f(hacc[rfi][cf][g * 4 + j]));
            // phase-local row = w*64 + rfi*32 + g*8 + lh*4 + j
            const int kg = w * 8 + rfi * 4 + g;
            const int ui = (kg * 64 + cf * 32 + l31) * 8 + lh * 4;
            *reinterpret_cast<ushort4v*>(&hs[ui]) = *reinterpret_cast<const ushort4v*>(pk);
          }
        }
      __syncthreads();
      // stage2: out rows w*64..+64 (rb = w*2 + rfi), K = this phase's 256
      {
        const unsigned short* A0 =
            w2p + ((size_t)(e * 8 + w * 2) * 32 + ph * 16) * 512 + l * 8;
        gemm_k256(A0, A0 + 16384, hB0, hB1, oacc);
      }
    }
  }

  // ---- write out[b, o, px] ----
#pragma unroll
  for (int rfi = 0; rfi < 2; ++rfi)
#pragma unroll
    for (int cf = 0; cf < 2; ++cf)
#pragma unroll
      for (int r = 0; r < 16; ++r) {
        const int o = w * 64 + rfi * 32 + (r & 3) + 8 * (r >> 2) + 4 * lh;
        out[((size_t)b * 256 + o) * HW + px0 + cf * 32 + l31] = oacc[rfi][cf][r];
      }
}

extern "C" void kernel_launch(void* const* d_in, const int* in_sizes, int n_in,
                              void* d_out, int out_size, void* d_ws, size_t ws_size,
                              hipStream_t stream) {
  const float* x = (const float*)d_in[0];
  const float* rw1 = (const float*)d_in[1];
  const float* rw2 = (const float*)d_in[2];
  const float* ew1 = (const float*)d_in[3];
  const float* ew2 = (const float*)d_in[4];
  const float* shw = (const float*)d_in[5];
  float* out = (float*)d_out;
  char* ws = (char*)d_ws;

  float* xp = (float*)(ws);                                // 3,211,264 B
  float* hsum = (float*)(ws + 3211264);
  float* selv = (float*)(ws + 3213312);
  int* sele = (int*)(ws + 3213440);
  unsigned short* wshp = (unsigned short*)(ws + 3213568);  // 128 KB
  unsigned short* w1p = wshp + 65536;                      // 1 MB
  unsigned short* w2p = w1p + 524288;                      // 1 MB

  prep_k<<<7488, 256, 0, stream>>>(shw, ew1, ew2, x, wshp, w1p, w2p, xp);
  router_conv_k<<<512, 256, 0, stream>>>(xp, rw1, hsum);
  topk_k<<<1, 64, 0, stream>>>(hsum, rw2, selv, sele);
  moe_main_k<<<784, 256, 0, stream>>>(x, wshp, w1p, w2p, selv, sele, out);
}

// Round 4
// 167.583 us; speedup vs baseline: 1.4946x; 1.0073x over previous
//
#include <hip/hip_runtime.h>
#include <hip/hip_bf16.h>

typedef __attribute__((ext_vector_type(8))) short bf16x8;
typedef __attribute__((ext_vector_type(16))) float f32x16;
typedef __attribute__((ext_vector_type(4))) unsigned short ushort4v;

static __device__ __forceinline__ unsigned short f2bf(float f) {
  unsigned u = __float_as_uint(f);
  return (unsigned short)((u + 0x7FFFu + ((u >> 16) & 1u)) >> 16);
}
static __device__ __forceinline__ float silu_f(float v) { return v / (1.f + __expf(-v)); }

// ---- K0: fused weight pack (A-fragment order) + 4x4 avg pool ----
// A-frag pack: lane l holds row rb*32+(l&31), k = ks*16 + (l>>5)*8 + i.
// packed[((rb*NKS+ks)*64 + l)*8 + i]
__global__ void prep_k(const float* __restrict__ shw, const float* __restrict__ ew1,
                       const float* __restrict__ ew2, const float* __restrict__ x,
                       unsigned short* __restrict__ wshp, unsigned short* __restrict__ w1p,
                       unsigned short* __restrict__ w2p, float* __restrict__ xp) {
  const int bid = blockIdx.x;
  if (bid < 4352) {
    int idx = bid * 256 + threadIdx.x;
    if (idx < 65536) {  // shared_w [256,256], NKS=16
      int j = idx;
      int i = j & 7, l = (j >> 3) & 63, ks = (j >> 9) & 15, rb = j >> 13;
      int row = rb * 32 + (l & 31), k = ks * 16 + (l >> 5) * 8 + i;
      wshp[j] = f2bf(shw[row * 256 + k]);
    } else if (idx < 589824) {  // expert_w1 [4,512,256], NKS=16
      int j = idx - 65536;
      int i = j & 7, l = (j >> 3) & 63, ks = (j >> 9) & 15, rb = (j >> 13) & 15, e = j >> 17;
      int row = rb * 32 + (l & 31), k = ks * 16 + (l >> 5) * 8 + i;
      w1p[j] = f2bf(ew1[((size_t)e * 512 + row) * 256 + k]);
    } else if (idx < 1114112) {  // expert_w2 [4,256,512], NKS=32
      int j = idx - 589824;
      int i = j & 7, l = (j >> 3) & 63, ks = (j >> 9) & 31, rb = (j >> 14) & 7, e = j >> 17;
      int row = rb * 32 + (l & 31), k = ks * 16 + (l >> 5) * 8 + i;
      w2p[j] = f2bf(ew2[((size_t)e * 256 + row) * 512 + k]);
    }
  } else {
    int idx = (bid - 4352) * 256 + threadIdx.x;
    if (idx >= 16 * 256 * 196) return;
    int pj = idx % 14, tmp = idx / 14, pi = tmp % 14, bc = tmp / 14;
    const float* src = x + (size_t)bc * 3136 + pi * 4 * 56 + pj * 4;
    float s = 0.f;
#pragma unroll
    for (int u = 0; u < 4; ++u) {
      float4 v = *reinterpret_cast<const float4*>(src + u * 56);
      s += v.x + v.y + v.z + v.w;
    }
    xp[idx] = s * 0.0625f;
  }
}

// ---- K2: router 3x3 conv (pad 1) + SiLU + spatial sum -> hsum[16,32] ----
__global__ __launch_bounds__(256) void router_conv_k(const float* __restrict__ xp,
                                                     const float* __restrict__ rw1,
                                                     float* __restrict__ hsum) {
  const int b = blockIdx.x >> 5, r = blockIdx.x & 31;
  __shared__ float wl[2304];
  __shared__ float xl[32][256];
  __shared__ float red[4];
  const int t = threadIdx.x;
  for (int i = t; i < 2304; i += 256) wl[i] = rw1[r * 2304 + i];
  for (int i = t; i < 32 * 256; i += 256) (&xl[0][0])[i] = 0.f;
  const int pi = t / 14, pj = t % 14;
  float acc = 0.f;
  for (int cc = 0; cc < 8; ++cc) {
    __syncthreads();
    for (int i = t; i < 32 * 196; i += 256) {
      int c = i / 196, px = i % 196;
      xl[c][(px / 14 + 1) * 16 + (px % 14 + 1)] =
          xp[((size_t)b * 256 + cc * 32 + c) * 196 + px];
    }
    __syncthreads();
    if (t < 196) {
      for (int c = 0; c < 32; ++c) {
        const float* wp = &wl[(cc * 32 + c) * 9];
        const float* xc = &xl[c][pi * 16 + pj];
#pragma unroll
        for (int u = 0; u < 3; ++u)
#pragma unroll
          for (int v = 0; v < 3; ++v) acc += xc[u * 16 + v] * wp[u * 3 + v];
      }
    }
  }
  float s = (t < 196) ? silu_f(acc) : 0.f;
#pragma unroll
  for (int off = 32; off > 0; off >>= 1) s += __shfl_down(s, off);
  if ((t & 63) == 0) red[t >> 6] = s;
  __syncthreads();
  if (t == 0) hsum[b * 32 + r] = red[0] + red[1] + red[2] + red[3];
}

// ---- K3: logits -> softmax -> top-2 -> normalized weights ----
__global__ void topk_k(const float* __restrict__ hsum, const float* __restrict__ rw2,
                       float* __restrict__ selv, int* __restrict__ sele) {
  const int t = threadIdx.x;
  const int b = t >> 2, e = t & 3;
  float l = 0.f;
#pragma unroll
  for (int r = 0; r < 32; ++r) l += rw2[e * 32 + r] * hsum[b * 32 + r];
  l *= (1.f / 196.f);
  float m = fmaxf(l, __shfl_xor(l, 1));
  m = fmaxf(m, __shfl_xor(m, 2));
  float p = __expf(l - m);
  float sm = p + __shfl_xor(p, 1);
  sm += __shfl_xor(sm, 2);
  float prob = p / sm;
  float p0 = __shfl(prob, (b << 2) | 0);
  float p1 = __shfl(prob, (b << 2) | 1);
  float p2 = __shfl(prob, (b << 2) | 2);
  float p3 = __shfl(prob, (b << 2) | 3);
  if (e == 0) {
    float pr[4] = {p0, p1, p2, p3};
    int i1 = 0;
    for (int i = 1; i < 4; ++i)
      if (pr[i] > pr[i1]) i1 = i;
    int i2 = (i1 == 0) ? 1 : 0;
    for (int i = 0; i < 4; ++i) {
      if (i == i1 || i == i2) continue;
      if (pr[i] > pr[i2]) i2 = i;
    }
    float denom = pr[i1] + pr[i2] + 1e-6f;
    selv[b * 2 + 0] = pr[i1] / denom;
    selv[b * 2 + 1] = pr[i2] / denom;
    sele[b * 2 + 0] = i1;
    sele[b * 2 + 1] = i2;
  }
}

// K=256 GEMM step: 2 row-blocks x 2 px-blocks, depth-4 ring software pipeline.
// A0/A1: per-lane weight-frag pointers (stride 512 ushorts per ks, from L2).
// B0/B1: per-lane LDS frag pointers (stride 1024 ushorts per ks).
// Loads for ks+3 issued BEFORE the MFMA cluster of ks (~3 K-steps of latency cover).
static __device__ __forceinline__ void gemm_k256_p4(
    const unsigned short* __restrict__ A0, const unsigned short* __restrict__ A1,
    const unsigned short* B0, const unsigned short* B1, f32x16 acc[2][2]) {
  bf16x8 a0[4], a1[4], b0[4], b1[4];
#pragma unroll
  for (int s = 0; s < 3; ++s) {
    a0[s] = *reinterpret_cast<const bf16x8*>(A0 + s * 512);
    a1[s] = *reinterpret_cast<const bf16x8*>(A1 + s * 512);
    b0[s] = *reinterpret_cast<const bf16x8*>(B0 + s * 1024);
    b1[s] = *reinterpret_cast<const bf16x8*>(B1 + s * 1024);
  }
#pragma unroll
  for (int ks = 0; ks < 16; ++ks) {
    const int s = ks & 3;
    const int n = (ks + 3) & 3;
    if (ks < 13) {
      a0[n] = *reinterpret_cast<const bf16x8*>(A0 + (ks + 3) * 512);
      a1[n] = *reinterpret_cast<const bf16x8*>(A1 + (ks + 3) * 512);
      b0[n] = *reinterpret_cast<const bf16x8*>(B0 + (ks + 3) * 1024);
      b1[n] = *reinterpret_cast<const bf16x8*>(B1 + (ks + 3) * 1024);
    }
    __builtin_amdgcn_s_setprio(1);
    acc[0][0] = __builtin_amdgcn_mfma_f32_32x32x16_bf16(a0[s], b0[s], acc[0][0], 0, 0, 0);
    acc[0][1] = __builtin_amdgcn_mfma_f32_32x32x16_bf16(a0[s], b1[s], acc[0][1], 0, 0, 0);
    acc[1][0] = __builtin_amdgcn_mfma_f32_32x32x16_bf16(a1[s], b0[s], acc[1][0], 0, 0, 0);
    acc[1][1] = __builtin_amdgcn_mfma_f32_32x32x16_bf16(a1[s], b1[s], acc[1][1], 0, 0, 0);
    __builtin_amdgcn_s_setprio(0);
  }
}

// ---- K4: fused MoE main. 4 waves x 64px, rf=2 cf=2, frag-linear LDS ----
// xs/hs layout: [kgroup 0..31][px 0..63][8 ushorts] -- B-frags contiguous.
__global__ __launch_bounds__(256, 2) void moe_main_k(
    const float* __restrict__ x, const unsigned short* __restrict__ wshp,
    const unsigned short* __restrict__ w1p, const unsigned short* __restrict__ w2p,
    const float* __restrict__ selv, const int* __restrict__ sele,
    float* __restrict__ out) {
  constexpr int HW = 3136;
  __shared__ __align__(16) unsigned short xs[32 * 64 * 8];  // 32 KB
  __shared__ __align__(16) unsigned short hs[32 * 64 * 8];  // 32 KB

  const int b = blockIdx.x / 49, tile = blockIdx.x - b * 49;
  const int px0 = tile * 64;
  const int t = threadIdx.x;
  const int w = t >> 6, l = t & 63;
  const int l31 = l & 31, lh = l >> 5;

  // ---- stage x tile: thread handles px=l, channels w*64+cg*8+i ----
  {
    const float* xb = x + (size_t)b * 256 * HW + px0 + l;
#pragma unroll
    for (int cg = 0; cg < 8; ++cg) {
      const int c0 = w * 64 + cg * 8;
      alignas(16) unsigned short tmp[8];
#pragma unroll
      for (int i = 0; i < 8; ++i) tmp[i] = f2bf(xb[(size_t)(c0 + i) * HW]);
      *reinterpret_cast<bf16x8*>(&xs[((c0 >> 3) * 64 + l) * 8]) =
          *reinterpret_cast<const bf16x8*>(tmp);
    }
  }

  // per-lane B-frag base pointers (k element = (l>>5)*8 + i)
  const unsigned short* xB0 = xs + (lh * 64 + l31) * 8;
  const unsigned short* xB1 = xB0 + 32 * 8;
  const unsigned short* hB0 = hs + (lh * 64 + l31) * 8;
  const unsigned short* hB1 = hB0 + 32 * 8;

  f32x16 oacc[2][2];
#pragma unroll
  for (int i = 0; i < 2; ++i)
#pragma unroll
    for (int j = 0; j < 2; ++j)
#pragma unroll
      for (int r = 0; r < 16; ++r) oacc[i][j][r] = 0.f;

  __syncthreads();

  // ---- shared expert: out rows w*64..+64 (rb = w*2, w*2+1), K=256 ----
  {
    const unsigned short* A0 = wshp + (size_t)(w * 2) * 16 * 512 + l * 8;
    gemm_k256_p4(A0, A0 + 8192, xB0, xB1, oacc);
  }
#pragma unroll
  for (int i = 0; i < 2; ++i)
#pragma unroll
    for (int j = 0; j < 2; ++j)
#pragma unroll
      for (int r = 0; r < 16; ++r) oacc[i][j][r] = silu_f(oacc[i][j][r]);

  // ---- top-2 experts: hidden 512 rows in 2 phases of 256 ----
#pragma unroll 1
  for (int ei = 0; ei < 2; ++ei) {
    const int e = sele[b * 2 + ei];
    const float v = selv[b * 2 + ei];
#pragma unroll 1
    for (int ph = 0; ph < 2; ++ph) {
      f32x16 hacc[2][2];
#pragma unroll
      for (int i = 0; i < 2; ++i)
#pragma unroll
        for (int j = 0; j < 2; ++j)
#pragma unroll
          for (int r = 0; r < 16; ++r) hacc[i][j][r] = 0.f;
      // stage1: hid rows ph*256 + w*64 ..+64 (rb = ph*8 + w*2 + rfi), K=256
      {
        const unsigned short* A0 =
            w1p + (size_t)(e * 16 + ph * 8 + w * 2) * 16 * 512 + l * 8;
        gemm_k256_p4(A0, A0 + 8192, xB0, xB1, hacc);
      }
      __syncthreads();  // previous stage2 readers of hs are done
      // v*silu(hid) -> bf16 -> hs (frag-linear 8B writes)
#pragma unroll
      for (int rfi = 0; rfi < 2; ++rfi)
#pragma unroll
        for (int cf = 0; cf < 2; ++cf) {
#pragma unroll
          for (int g = 0; g < 4; ++g) {
            alignas(8) unsigned short pk[4];
#pragma unroll
            for (int j = 0; j < 4; ++j)
              pk[j] = f2bf(v * silu_f(hacc[rfi][cf][g * 4 + j]));
            // phase-local row = w*64 + rfi*32 + g*8 + lh*4 + j
            const int kg = w * 8 + rfi * 4 + g;
            const int ui = (kg * 64 + cf * 32 + l31) * 8 + lh * 4;
            *reinterpret_cast<ushort4v*>(&hs[ui]) = *reinterpret_cast<const ushort4v*>(pk);
          }
        }
      __syncthreads();
      // stage2: out rows w*64..+64 (rb = w*2 + rfi), K = this phase's 256
      {
        const unsigned short* A0 =
            w2p + ((size_t)(e * 8 + w * 2) * 32 + ph * 16) * 512 + l * 8;
        gemm_k256_p4(A0, A0 + 16384, hB0, hB1, oacc);
      }
    }
  }

  // ---- write out[b, o, px] ----
#pragma unroll
  for (int rfi = 0; rfi < 2; ++rfi)
#pragma unroll
    for (int cf = 0; cf < 2; ++cf)
#pragma unroll
      for (int r = 0; r < 16; ++r) {
        const int o = w * 64 + rfi * 32 + (r & 3) + 8 * (r >> 2) + 4 * lh;
        out[((size_t)b * 256 + o) * HW + px0 + cf * 32 + l31] = oacc[rfi][cf][r];
      }
}

extern "C" void kernel_launch(void* const* d_in, const int* in_sizes, int n_in,
                              void* d_out, int out_size, void* d_ws, size_t ws_size,
                              hipStream_t stream) {
  const float* x = (const float*)d_in[0];
  const float* rw1 = (const float*)d_in[1];
  const float* rw2 = (const float*)d_in[2];
  const float* ew1 = (const float*)d_in[3];
  const float* ew2 = (const float*)d_in[4];
  const float* shw = (const float*)d_in[5];
  float* out = (float*)d_out;
  char* ws = (char*)d_ws;

  float* xp = (float*)(ws);                                // 3,211,264 B
  float* hsum = (float*)(ws + 3211264);
  float* selv = (float*)(ws + 3213312);
  int* sele = (int*)(ws + 3213440);
  unsigned short* wshp = (unsigned short*)(ws + 3213568);  // 128 KB
  unsigned short* w1p = wshp + 65536;                      // 1 MB
  unsigned short* w2p = w1p + 524288;                      // 1 MB

  prep_k<<<7488, 256, 0, stream>>>(shw, ew1, ew2, x, wshp, w1p, w2p, xp);
  router_conv_k<<<512, 256, 0, stream>>>(xp, rw1, hsum);
  topk_k<<<1, 64, 0, stream>>>(hsum, rw2, selv, sele);
  moe_main_k<<<784, 256, 0, stream>>>(x, wshp, w1p, w2p, selv, sele, out);
}